// Round 8
// baseline (270.593 us; speedup 1.0000x reference)
//
#include <hip/hip_runtime.h>

#define OUT_F 11008
#define IN_F  4096
#define NBATCH 8
#define R 4                       // output rows per wave
#define BLOCK 64                  // one wave per block
#define COLS_PER_BLOCK 1024
#define CHUNKS (IN_F / COLS_PER_BLOCK)   // 4 column-chunks per row-group
#define ITERS  (COLS_PER_BLOCK / 256)    // 4 iters x 256 cols (4 cols/lane)

// One wave: 4 rows x 1024 cols. No LDS, no barriers, no software pipeline.
// Latency hiding = wave oversubscription (11008 waves, each stalls holding
// 12KB of loads in flight). LUT gathers via ds_bpermute from a register
// table. Partials combined with fp32 atomicAdd into zeroed out[].
__global__ __launch_bounds__(BLOCK) void pal_linear_kernel(
    const float* __restrict__ x,        // [8, 4096]
    const int*   __restrict__ widx,     // [11008*4096] in [0,16)
    const float* __restrict__ lut,      // [352256, 16] f32 on device
    const float* __restrict__ bias,     // [11008]
    float* __restrict__ out)            // [8, 11008], pre-zeroed
{
    const int lane  = threadIdx.x;
    const int rowG  = blockIdx.x >> 2;          // 0..2751
    const int chunk = blockIdx.x & 3;           // 0..3
    const int o0    = rowG * R;
    const int cbase = chunk * COLS_PER_BLOCK;
    const int hb    = (lane & 32) << 1;         // +64B: hi half-wave uses group g0+1

    float acc[R][NBATCH];
#pragma unroll
    for (int r = 0; r < R; ++r)
#pragma unroll
        for (int m = 0; m < NBATCH; ++m) acc[r][m] = 0.0f;

#pragma unroll 1
    for (int it = 0; it < ITERS; ++it) {
        const int c0 = cbase + it * 256;
        const int cl = c0 + 4 * lane;

        // 1) idx stream (the 180MB floor) — 4x coalesced int4
        int4 idx[R];
#pragma unroll
        for (int r = 0; r < R; ++r)
            idx[r] = *reinterpret_cast<const int4*>(
                widx + (size_t)(o0 + r) * IN_F + cl);

        // 2) LUT table regs: lane j holds lut[row][g0*16 + (j&31)]
        //    (entries of groups g0 (lanes 0-15) and g0+1 (lanes 16-31))
        float tab[R];
#pragma unroll
        for (int r = 0; r < R; ++r)
            tab[r] = lut[((size_t)(o0 + r) * 32 + (c0 >> 7)) * 16 + (lane & 31)];

        // 3) x (L2-hot)
        float4 xv[NBATCH];
#pragma unroll
        for (int m = 0; m < NBATCH; ++m)
            xv[m] = *reinterpret_cast<const float4*>(x + m * IN_F + cl);

        // 4) weight gather: pull entry from the lane holding it
        float w[R][4];
#pragma unroll
        for (int r = 0; r < R; ++r) {
            const int t = __float_as_int(tab[r]);
            w[r][0] = __int_as_float(__builtin_amdgcn_ds_bpermute((idx[r].x << 2) + hb, t));
            w[r][1] = __int_as_float(__builtin_amdgcn_ds_bpermute((idx[r].y << 2) + hb, t));
            w[r][2] = __int_as_float(__builtin_amdgcn_ds_bpermute((idx[r].z << 2) + hb, t));
            w[r][3] = __int_as_float(__builtin_amdgcn_ds_bpermute((idx[r].w << 2) + hb, t));
        }

        // 5) FMAs — all static indexing
#pragma unroll
        for (int m = 0; m < NBATCH; ++m)
#pragma unroll
            for (int r = 0; r < R; ++r) {
                float a = acc[r][m];
                a = fmaf(w[r][0], xv[m].x, a);
                a = fmaf(w[r][1], xv[m].y, a);
                a = fmaf(w[r][2], xv[m].z, a);
                a = fmaf(w[r][3], xv[m].w, a);
                acc[r][m] = a;
            }
    }

    // ---- reduction: fold across halves, pack even/odd m into lane halves ----
    float f[R][NBATCH];
#pragma unroll
    for (int r = 0; r < R; ++r)
#pragma unroll
        for (int m = 0; m < NBATCH; ++m)
            f[r][m] = acc[r][m] + __shfl_xor(acc[r][m], 32, 64);
    // both halves now identical per value; lanes<32 carry even m, >=32 odd m
    float e[16];
#pragma unroll
    for (int r = 0; r < R; ++r)
#pragma unroll
        for (int q = 0; q < 4; ++q)
            e[r * 4 + q] = (lane < 32) ? f[r][2 * q] : f[r][2 * q + 1];
#pragma unroll
    for (int off = 16; off >= 1; off >>= 1)     // xor 16,8,4,2,1: never crosses halves
#pragma unroll
        for (int p = 0; p < 16; ++p)
            e[p] += __shfl_xor(e[p], off, 64);

    // writers: lane p<16 -> (r=p>>2, m=2q); lane 32+p -> m=2q+1
    const int p = lane & 15;
    float v = 0.0f;
#pragma unroll
    for (int pp = 0; pp < 16; ++pp)
        if (p == pp) v = e[pp];                 // static cndmask chain (R5 lesson)

    const bool lo = (lane < 16);
    const bool hi = (lane >= 32) && (lane < 48);
    if (lo || hi) {
        const int r   = p >> 2;
        const int m   = 2 * (p & 3) + (lo ? 0 : 1);
        const int row = o0 + r;
        if (chunk == 0) v += bias[row];         // bias added exactly once
        atomicAdd(out + (size_t)m * OUT_F + row, v);
    }
}

extern "C" void kernel_launch(void* const* d_in, const int* in_sizes, int n_in,
                              void* d_out, int out_size, void* d_ws, size_t ws_size,
                              hipStream_t stream) {
    const float* x    = (const float*)d_in[0];
    const int*   widx = (const int*)d_in[1];
    const float* lut  = (const float*)d_in[2];
    const float* bias = (const float*)d_in[3];
    float* out = (float*)d_out;

    hipMemsetAsync(out, 0, (size_t)out_size * sizeof(float), stream);
    pal_linear_kernel<<<(OUT_F / R) * CHUNKS, BLOCK, 0, stream>>>(
        x, widx, lut, bias, out);
}